// Round 5
// baseline (243.961 us; speedup 1.0000x reference)
//
#include <hip/hip_runtime.h>

// Problem constants
#define BB 4
#define SS 2048
#define DD 512
#define HH 8
#define DKK 64
#define HDK 512   // H*DK

typedef __attribute__((ext_vector_type(4))) float f32x4;
typedef __attribute__((ext_vector_type(8))) __bf16 bf16x8;
typedef __attribute__((ext_vector_type(4))) __bf16 bf16x4;

#define MFMA16(a, b, c) __builtin_amdgcn_mfma_f32_16x16x32_bf16((a), (b), (c), 0, 0, 0)

__device__ inline bf16x8 cvt8(const float4 a, const float4 b) {
    bf16x8 w;
    w[0] = (__bf16)a.x; w[1] = (__bf16)a.y; w[2] = (__bf16)a.z; w[3] = (__bf16)a.w;
    w[4] = (__bf16)b.x; w[5] = (__bf16)b.y; w[6] = (__bf16)b.z; w[7] = (__bf16)b.w;
    return w;
}

// ---------------------------------------------------------------------------
// Kernel 1: fused convert + projection GEMM, 128x128 tile, BK=64, 4 waves
// (2x2), 64x64 per wave = 4x4 fragments of 16x16 -> 32 MFMA per wave-K-step.
// LDS tiles XOR-swizzled (byte ^= (row&7)<<4), reg-staged write + read.
//   z=0 -> qh [B,H,S,DK], z=1 -> kh [B,H,S,DK], z=2 -> vt [B,H,DK,S]
// ---------------------------------------------------------------------------
__global__ __launch_bounds__(256) void proj_kernel(
    const float* __restrict__ q, const float* __restrict__ k, const float* __restrict__ v,
    const float* __restrict__ Wq, const float* __restrict__ bq,
    __bf16* __restrict__ qh, __bf16* __restrict__ kh, __bf16* __restrict__ vt)
{
    const int z  = blockIdx.z;
    const float* X = (z == 0) ? q : (z == 1) ? k : v;
    const int m0 = blockIdx.x * 128;
    const int n0 = blockIdx.y * 128;

    __shared__ __align__(16) __bf16 As[128 * 64];   // swizzled
    __shared__ __align__(16) __bf16 Bs[128 * 64];
    char* AsB = (char*)As;
    char* BsB = (char*)Bs;

    const int t    = threadIdx.x;
    const int lane = t & 63, wid = t >> 6;
    const int lo   = lane & 15, hi = lane >> 4;
    const int wm   = wid >> 1, wn = wid & 1;

    // staging geometry: 2 threads per row, 32 fp32 each
    const int srow  = t >> 1;            // 0..127
    const int shalf = (t & 1) * 32;      // 0 or 32 (bf16/fp32 cols)
    const int sswz  = (srow & 7) << 4;

    f32x4 acc[4][4] = {};

    for (int k0 = 0; k0 < DD; k0 += 64) {
        // global loads + convert in regs BEFORE the barrier
        float4 xa[8], xb[8];
#pragma unroll
        for (int i = 0; i < 8; ++i) {
            xa[i] = *reinterpret_cast<const float4*>(&X [(size_t)(m0 + srow) * DD + k0 + shalf + 4 * i]);
            xb[i] = *reinterpret_cast<const float4*>(&Wq[(size_t)(n0 + srow) * DD + k0 + shalf + 4 * i]);
        }
        bf16x8 wa[4], wb[4];
#pragma unroll
        for (int j = 0; j < 4; ++j) {
            wa[j] = cvt8(xa[2 * j], xa[2 * j + 1]);
            wb[j] = cvt8(xb[2 * j], xb[2 * j + 1]);
        }
        __syncthreads();   // previous compute's LDS reads done
#pragma unroll
        for (int j = 0; j < 4; ++j) {
            const int cb = ((shalf + 8 * j) * 2) ^ sswz;
            *reinterpret_cast<bf16x8*>(AsB + srow * 128 + cb) = wa[j];
            *reinterpret_cast<bf16x8*>(BsB + srow * 128 + cb) = wb[j];
        }
        __syncthreads();   // tile visible

#pragma unroll
        for (int kk = 0; kk < 2; ++kk) {
            bf16x8 a[4], b[4];
#pragma unroll
            for (int mi = 0; mi < 4; ++mi) {
                const int row = wm * 64 + mi * 16 + lo;
                a[mi] = *reinterpret_cast<const bf16x8*>(
                    AsB + row * 128 + ((kk * 64 + hi * 16) ^ ((row & 7) << 4)));
            }
#pragma unroll
            for (int ni = 0; ni < 4; ++ni) {
                const int row = wn * 64 + ni * 16 + lo;
                b[ni] = *reinterpret_cast<const bf16x8*>(
                    BsB + row * 128 + ((kk * 64 + hi * 16) ^ ((row & 7) << 4)));
            }
#pragma unroll
            for (int mi = 0; mi < 4; ++mi)
#pragma unroll
                for (int ni = 0; ni < 4; ++ni)
                    acc[mi][ni] = MFMA16(a[mi], b[ni], acc[mi][ni]);
        }
    }

    // Epilogue: n = col(lane&15)-indexed, m = 4*hi+r (R1-verified convention)
#pragma unroll
    for (int mi = 0; mi < 4; ++mi) {
#pragma unroll
        for (int ni = 0; ni < 4; ++ni) {
            const int n = n0 + wn * 64 + ni * 16 + lo;
            const float bias = bq[n];
            const int h_ = n >> 6, e_ = n & 63;
#pragma unroll
            for (int r = 0; r < 4; ++r) {
                const int m = m0 + wm * 64 + mi * 16 + hi * 4 + r;
                const float val = acc[mi][ni][r] + bias;
                const int b_ = m >> 11, s_ = m & (SS - 1);
                const size_t bh = (size_t)(b_ * HH + h_);
                if (z == 0)
                    qh[(bh * SS + s_) * DKK + e_] = (__bf16)val;
                else if (z == 1)
                    kh[(bh * SS + s_) * DKK + e_] = (__bf16)val;
                else
                    vt[(bh * DKK + e_) * SS + s_] = (__bf16)val;
            }
        }
    }
}

// ---------------------------------------------------------------------------
// Kernel 2: flash attention, swapped-QK^T. 16 q-rows/wave, 64 q-rows/block,
// KV tile = 64. Grid 1024 blocks -> ~4 blocks/CU (occupancy fix vs R2's 2).
// Lane (lo,hi) holds S^T[kv=16f+4hi+r][q=lo]. Softmax: 15 in-reg fmax +
// 2 shfl_xor; P staged per-wave (no block barrier). O^T = mfma(V^T, P^T).
// K/V LDS XOR-swizzled both sides.
// ---------------------------------------------------------------------------
__global__ __launch_bounds__(256) void attn_kernel(
    const __bf16* __restrict__ qh, const __bf16* __restrict__ kh,
    const __bf16* __restrict__ vt, __bf16* __restrict__ concat)
{
    const int q0 = blockIdx.x * 64;
    const int bh = blockIdx.y;                 // b*H + h
    const int b_ = bh >> 3, h_ = bh & 7;
    const size_t base = (size_t)bh * SS * DKK;
    const __bf16* qhp = qh + base;
    const __bf16* khp = kh + base;
    const __bf16* vtp = vt + base;             // [DK][S] per (b,h)

    const int t    = threadIdx.x;
    const int lane = t & 63, wid = t >> 6;
    const int lo   = lane & 15, hi = lane >> 4;

    __shared__ __align__(16) __bf16 Ks[64 * 64];    // swizzled [kv][d]
    __shared__ __align__(16) __bf16 Vts[64 * 64];   // swizzled [e][kv]
    __shared__ __align__(16) __bf16 Ps[4][16][72];  // per-wave P [q][kv], padded

    char* KsB  = (char*)Ks;
    char* VtsB = (char*)Vts;

    // staging: wave w stages rows [16w,16w+16) of K and V^T
    const int sr   = lane >> 3;                  // 0..7
    const int gcb  = (lane & 7) << 4;            // linear col byte
    const int scb  = gcb ^ (sr << 4);            // swizzled col byte
    const int srow = 16 * wid + sr;

    // Q fragments in registers for the whole loop (wave's 16 q-rows)
    bf16x8 qf[2];
#pragma unroll
    for (int kk = 0; kk < 2; ++kk)
        qf[kk] = *reinterpret_cast<const bf16x8*>(
            &qhp[(size_t)(q0 + 16 * wid + lo) * DKK + 32 * kk + 8 * hi]);

    f32x4 acc[4] = {};                           // [e-frag]
    float m_run = -INFINITY, l_run = 0.f;

    for (int kv0 = 0; kv0 < SS; kv0 += 64) {
        bf16x8 kr0 = *reinterpret_cast<const bf16x8*>(
            (const char*)&khp[(size_t)(kv0 + srow) * DKK] + gcb);
        bf16x8 kr1 = *reinterpret_cast<const bf16x8*>(
            (const char*)&khp[(size_t)(kv0 + srow + 8) * DKK] + gcb);
        bf16x8 vr0 = *reinterpret_cast<const bf16x8*>(
            (const char*)&vtp[(size_t)srow * SS + kv0] + gcb);
        bf16x8 vr1 = *reinterpret_cast<const bf16x8*>(
            (const char*)&vtp[(size_t)(srow + 8) * SS + kv0] + gcb);

        __syncthreads();
        *reinterpret_cast<bf16x8*>(KsB  + srow * 128 + scb)       = kr0;
        *reinterpret_cast<bf16x8*>(KsB  + (srow + 8) * 128 + scb) = kr1;
        *reinterpret_cast<bf16x8*>(VtsB + srow * 128 + scb)       = vr0;
        *reinterpret_cast<bf16x8*>(VtsB + (srow + 8) * 128 + scb) = vr1;
        __syncthreads();

        // ---- scores: S^T[kv 64][q 16] via mfma(K, Q) ----
        f32x4 sc[4] = {};
#pragma unroll
        for (int kk = 0; kk < 2; ++kk) {
            bf16x8 kf[4];
#pragma unroll
            for (int f = 0; f < 4; ++f) {
                const int row = 16 * f + lo;
                const int cb  = (64 * kk + 16 * hi) ^ ((row & 7) << 4);
                kf[f] = *reinterpret_cast<const bf16x8*>(KsB + row * 128 + cb);
            }
#pragma unroll
            for (int f = 0; f < 4; ++f)
                sc[f] = MFMA16(kf[f], qf[kk], sc[f]);
        }

        // ---- online softmax (lane owns q = lo) ----
        {
            float mx = -1e30f;
#pragma unroll
            for (int f = 0; f < 4; ++f)
#pragma unroll
                for (int r = 0; r < 4; ++r)
                    mx = fmaxf(mx, sc[f][r]);
            mx = fmaxf(mx, __shfl_xor(mx, 16));
            mx = fmaxf(mx, __shfl_xor(mx, 32));
            const float mnew = fmaxf(m_run, mx * 0.125f);
            const float scl  = __expf(m_run - mnew);
            float rs = 0.f;
#pragma unroll
            for (int f = 0; f < 4; ++f) {
                bf16x4 pk;
#pragma unroll
                for (int r = 0; r < 4; ++r) {
                    const float e = __expf(fmaf(sc[f][r], 0.125f, -mnew));
                    rs += e;
                    pk[r] = (__bf16)e;
                }
                *reinterpret_cast<bf16x4*>(&Ps[wid][lo][16 * f + 4 * hi]) = pk;
            }
            rs += __shfl_xor(rs, 16);
            rs += __shfl_xor(rs, 32);
            l_run = l_run * scl + rs;
            m_run = mnew;
#pragma unroll
            for (int f = 0; f < 4; ++f)
                acc[f] *= scl;
        }
        // no block barrier: Ps is per-wave, wave-internal ordering suffices

        // ---- PV: O^T += mfma(V^T, P^T) ----
#pragma unroll
        for (int kk = 0; kk < 2; ++kk) {
            bf16x8 pb = *reinterpret_cast<const bf16x8*>(&Ps[wid][lo][32 * kk + 8 * hi]);
#pragma unroll
            for (int f = 0; f < 4; ++f) {
                const int row = 16 * f + lo;                     // e index
                const int cb  = (64 * kk + 16 * hi) ^ ((row & 7) << 4);
                bf16x8 vf = *reinterpret_cast<const bf16x8*>(VtsB + row * 128 + cb);
                acc[f] = MFMA16(vf, pb, acc[f]);
            }
        }
    }

    // ---- epilogue ----
    {
        const float inv = 1.0f / l_run;
        const int qrow = q0 + 16 * wid + lo;
        const size_t ob = ((size_t)b_ * SS + qrow) * HDK + h_ * DKK;
#pragma unroll
        for (int f = 0; f < 4; ++f) {
            bf16x4 o;
#pragma unroll
            for (int r = 0; r < 4; ++r)
                o[r] = (__bf16)(acc[f][r] * inv);
            *reinterpret_cast<bf16x4*>(&concat[ob + 16 * f + 4 * hi]) = o;
        }
    }
}

// ---------------------------------------------------------------------------
// Kernel 3: output projection, same 128x128xBK64 structure as proj_kernel.
// A = concat (bf16 already), B = Wout (fp32 -> bf16 in staging).
// ---------------------------------------------------------------------------
__global__ __launch_bounds__(256) void outproj_kernel(
    const __bf16* __restrict__ concat, const float* __restrict__ Wout,
    const float* __restrict__ bout, float* __restrict__ out)
{
    const int m0 = blockIdx.x * 128;
    const int n0 = blockIdx.y * 128;

    __shared__ __align__(16) __bf16 As[128 * 64];
    __shared__ __align__(16) __bf16 Bs[128 * 64];
    char* AsB = (char*)As;
    char* BsB = (char*)Bs;

    const int t    = threadIdx.x;
    const int lane = t & 63, wid = t >> 6;
    const int lo   = lane & 15, hi = lane >> 4;
    const int wm   = wid >> 1, wn = wid & 1;

    const int srow  = t >> 1;
    const int shalf = (t & 1) * 32;
    const int sswz  = (srow & 7) << 4;

    f32x4 acc[4][4] = {};

    for (int k0 = 0; k0 < HDK; k0 += 64) {
        bf16x8 wa[4];
#pragma unroll
        for (int j = 0; j < 4; ++j)
            wa[j] = *reinterpret_cast<const bf16x8*>(
                &concat[(size_t)(m0 + srow) * HDK + k0 + shalf + 8 * j]);
        float4 xb[8];
#pragma unroll
        for (int i = 0; i < 8; ++i)
            xb[i] = *reinterpret_cast<const float4*>(
                &Wout[(size_t)(n0 + srow) * HDK + k0 + shalf + 4 * i]);
        bf16x8 wb[4];
#pragma unroll
        for (int j = 0; j < 4; ++j)
            wb[j] = cvt8(xb[2 * j], xb[2 * j + 1]);

        __syncthreads();
#pragma unroll
        for (int j = 0; j < 4; ++j) {
            const int cb = ((shalf + 8 * j) * 2) ^ sswz;
            *reinterpret_cast<bf16x8*>(AsB + srow * 128 + cb) = wa[j];
            *reinterpret_cast<bf16x8*>(BsB + srow * 128 + cb) = wb[j];
        }
        __syncthreads();

#pragma unroll
        for (int kk = 0; kk < 2; ++kk) {
            bf16x8 a[4], b[4];
#pragma unroll
            for (int mi = 0; mi < 4; ++mi) {
                const int row = wm * 64 + mi * 16 + lo;
                a[mi] = *reinterpret_cast<const bf16x8*>(
                    AsB + row * 128 + ((kk * 64 + hi * 16) ^ ((row & 7) << 4)));
            }
#pragma unroll
            for (int ni = 0; ni < 4; ++ni) {
                const int row = wn * 64 + ni * 16 + lo;
                b[ni] = *reinterpret_cast<const bf16x8*>(
                    BsB + row * 128 + ((kk * 64 + hi * 16) ^ ((row & 7) << 4)));
            }
#pragma unroll
            for (int mi = 0; mi < 4; ++mi)
#pragma unroll
                for (int ni = 0; ni < 4; ++ni)
                    acc[mi][ni] = MFMA16(a[mi], b[ni], acc[mi][ni]);
        }
    }

#pragma unroll
    for (int mi = 0; mi < 4; ++mi) {
#pragma unroll
        for (int ni = 0; ni < 4; ++ni) {
            const int n = n0 + wn * 64 + ni * 16 + lo;
            const float bias = bout[n];
#pragma unroll
            for (int r = 0; r < 4; ++r) {
                const int m = m0 + wm * 64 + mi * 16 + hi * 4 + r;
                out[(size_t)m * DD + n] = acc[mi][ni][r] + bias;
            }
        }
    }
}

// ---------------------------------------------------------------------------
extern "C" void kernel_launch(void* const* d_in, const int* in_sizes, int n_in,
                              void* d_out, int out_size, void* d_ws, size_t ws_size,
                              hipStream_t stream)
{
    (void)in_sizes; (void)n_in; (void)out_size; (void)ws_size;
    const float* q    = (const float*)d_in[0];
    const float* k    = (const float*)d_in[1];
    const float* v    = (const float*)d_in[2];
    const float* Wq   = (const float*)d_in[3];
    const float* bq   = (const float*)d_in[4];
    const float* Wout = (const float*)d_in[5];
    const float* bout = (const float*)d_in[6];
    float* out = (float*)d_out;

    char* ws = (char*)d_ws;
    __bf16* qh = (__bf16*)(ws);                      // 8 MiB  [B,H,S,DK]
    __bf16* kh = (__bf16*)(ws + (8u << 20));         // 8 MiB  [B,H,S,DK]
    __bf16* vt = (__bf16*)(ws + (16u << 20));        // 8 MiB  [B,H,DK,S]
    __bf16* cc = (__bf16*)(ws + (24u << 20));        // 8 MiB  [B,S,H*DK]

    proj_kernel<<<dim3(BB * SS / 128, HDK / 128, 3), 256, 0, stream>>>(q, k, v, Wq, bq, qh, kh, vt);
    attn_kernel<<<dim3(SS / 64, BB * HH), 256, 0, stream>>>(qh, kh, vt, cc);
    outproj_kernel<<<dim3(BB * SS / 128, DD / 128), 256, 0, stream>>>(cc, Wout, bout, out);
}

// Round 6
// 223.757 us; speedup vs baseline: 1.0903x; 1.0903x over previous
//
#include <hip/hip_runtime.h>

// Problem constants
#define BB 4
#define SS 2048
#define DD 512
#define HH 8
#define DKK 64
#define HDK 512   // H*DK

typedef __attribute__((ext_vector_type(4))) float f32x4;
typedef __attribute__((ext_vector_type(8))) __bf16 bf16x8;
typedef __attribute__((ext_vector_type(4))) __bf16 bf16x4;

#define MFMA16(a, b, c) __builtin_amdgcn_mfma_f32_16x16x32_bf16((a), (b), (c), 0, 0, 0)

// global -> LDS async DMA, 16 B per lane. LDS dest is wave-uniform base
// (HW writes lane i at base + 16*i); global src is per-lane (pre-swizzle here).
#define GLOAD_LDS16(gptr, lptr)                                                    \
    __builtin_amdgcn_global_load_lds(                                              \
        (const __attribute__((address_space(1))) void*)(gptr),                     \
        (__attribute__((address_space(3))) void*)(lptr), 16, 0, 0)

__device__ inline bf16x8 cvt48(const f32x4 f0, const f32x4 f1) {
    bf16x8 w;
    w[0] = (__bf16)f0[0]; w[1] = (__bf16)f0[1]; w[2] = (__bf16)f0[2]; w[3] = (__bf16)f0[3];
    w[4] = (__bf16)f1[0]; w[5] = (__bf16)f1[1]; w[6] = (__bf16)f1[2]; w[7] = (__bf16)f1[3];
    return w;
}

// ---------------------------------------------------------------------------
// Kernel 1: projection GEMM, 128x128 tile, BK=64, 4 waves (2x2), 64x64/wave.
// A = X (fp32), B = Wq (fp32): both staged fp32 to LDS via global_load_lds
// with pre-swizzled source chunks (chunk ^= row&7); converted to bf16 at
// fragment read. 2-barrier m97-style K-loop.
//   z=0 -> qh [B,H,S,DK], z=1 -> kh [B,H,S,DK], z=2 -> vt [B,H,DK,S]
// ---------------------------------------------------------------------------
__global__ __launch_bounds__(256) void proj_kernel(
    const float* __restrict__ q, const float* __restrict__ k, const float* __restrict__ v,
    const float* __restrict__ Wq, const float* __restrict__ bq,
    __bf16* __restrict__ qh, __bf16* __restrict__ kh, __bf16* __restrict__ vt)
{
    const int z  = blockIdx.z;
    const float* X = (z == 0) ? q : (z == 1) ? k : v;
    const int m0 = blockIdx.x * 128;
    const int n0 = blockIdx.y * 128;

    __shared__ __align__(16) float As[128 * 64];   // 32 KB, chunk-swizzled
    __shared__ __align__(16) float Bs[128 * 64];   // 32 KB

    const int t    = threadIdx.x;
    const int lane = t & 63, wid = t >> 6;
    const int lo   = lane & 15, hi = lane >> 4;
    const int wm   = wid >> 1, wn = wid & 1;

    // staging: per issue = 4 rows x 256 B = 1 KB; lane -> row r0+(lane>>4),
    // LDS chunk lane&15, global chunk (lane&15)^(row&7)
    const int srofs  = lane >> 4;
    const int schunk = lane & 15;

    f32x4 acc[4][4] = {};

    for (int k0 = 0; k0 < DD; k0 += 64) {
        __syncthreads();   // previous compute's LDS reads done
#pragma unroll
        for (int i = 0; i < 8; ++i) {
            const int r0  = 32 * wid + 4 * i;
            const int row = r0 + srofs;
            const int gco = ((schunk ^ (row & 7)) << 4);
            GLOAD_LDS16((const char*)&X [(size_t)(m0 + row) * DD + k0] + gco,
                        (char*)As + r0 * 256);
            GLOAD_LDS16((const char*)&Wq[(size_t)(n0 + row) * DD + k0] + gco,
                        (char*)Bs + r0 * 256);
        }
        __syncthreads();   // drains vmcnt -> tile visible

#pragma unroll
        for (int kk = 0; kk < 2; ++kk) {
            bf16x8 a[4], b[4];
#pragma unroll
            for (int mi = 0; mi < 4; ++mi) {
                const int ar = wm * 64 + mi * 16 + lo;
                const int rs = (ar & 7) << 4;
                const int cb = kk * 128 + hi * 32;
                f32x4 f0 = *reinterpret_cast<const f32x4*>((const char*)As + ar * 256 + (cb ^ rs));
                f32x4 f1 = *reinterpret_cast<const f32x4*>((const char*)As + ar * 256 + ((cb + 16) ^ rs));
                a[mi] = cvt48(f0, f1);
            }
#pragma unroll
            for (int ni = 0; ni < 4; ++ni) {
                const int br = wn * 64 + ni * 16 + lo;
                const int rs = (br & 7) << 4;
                const int cb = kk * 128 + hi * 32;
                f32x4 f0 = *reinterpret_cast<const f32x4*>((const char*)Bs + br * 256 + (cb ^ rs));
                f32x4 f1 = *reinterpret_cast<const f32x4*>((const char*)Bs + br * 256 + ((cb + 16) ^ rs));
                b[ni] = cvt48(f0, f1);
            }
#pragma unroll
            for (int mi = 0; mi < 4; ++mi)
#pragma unroll
                for (int ni = 0; ni < 4; ++ni)
                    acc[mi][ni] = MFMA16(a[mi], b[ni], acc[mi][ni]);
        }
    }

    // Epilogue: C/D col = lane&15 (n), row = 4*hi + r (m)  [R1-verified]
#pragma unroll
    for (int mi = 0; mi < 4; ++mi) {
#pragma unroll
        for (int ni = 0; ni < 4; ++ni) {
            const int n = n0 + wn * 64 + ni * 16 + lo;
            const float bias = bq[n];
            const int h_ = n >> 6, e_ = n & 63;
#pragma unroll
            for (int r = 0; r < 4; ++r) {
                const int m = m0 + wm * 64 + mi * 16 + hi * 4 + r;
                const float val = acc[mi][ni][r] + bias;
                const int b_ = m >> 11, s_ = m & (SS - 1);
                const size_t bh = (size_t)(b_ * HH + h_);
                if (z == 0)
                    qh[(bh * SS + s_) * DKK + e_] = (__bf16)val;
                else if (z == 1)
                    kh[(bh * SS + s_) * DKK + e_] = (__bf16)val;
                else
                    vt[(bh * DKK + e_) * SS + s_] = (__bf16)val;
            }
        }
    }
}

// ---------------------------------------------------------------------------
// Kernel 2: flash attention, swapped-QK^T. 16 q-rows/wave, 64 q-rows/block,
// KV tile = 64. (unchanged from R5)
// ---------------------------------------------------------------------------
__global__ __launch_bounds__(256) void attn_kernel(
    const __bf16* __restrict__ qh, const __bf16* __restrict__ kh,
    const __bf16* __restrict__ vt, __bf16* __restrict__ concat)
{
    const int q0 = blockIdx.x * 64;
    const int bh = blockIdx.y;                 // b*H + h
    const int b_ = bh >> 3, h_ = bh & 7;
    const size_t base = (size_t)bh * SS * DKK;
    const __bf16* qhp = qh + base;
    const __bf16* khp = kh + base;
    const __bf16* vtp = vt + base;             // [DK][S] per (b,h)

    const int t    = threadIdx.x;
    const int lane = t & 63, wid = t >> 6;
    const int lo   = lane & 15, hi = lane >> 4;

    __shared__ __align__(16) __bf16 Ks[64 * 64];    // swizzled [kv][d]
    __shared__ __align__(16) __bf16 Vts[64 * 64];   // swizzled [e][kv]
    __shared__ __align__(16) __bf16 Ps[4][16][72];  // per-wave P [q][kv], padded

    char* KsB  = (char*)Ks;
    char* VtsB = (char*)Vts;

    const int sr   = lane >> 3;                  // 0..7
    const int gcb  = (lane & 7) << 4;            // linear col byte
    const int scb  = gcb ^ (sr << 4);            // swizzled col byte
    const int srow = 16 * wid + sr;

    bf16x8 qf[2];
#pragma unroll
    for (int kk = 0; kk < 2; ++kk)
        qf[kk] = *reinterpret_cast<const bf16x8*>(
            &qhp[(size_t)(q0 + 16 * wid + lo) * DKK + 32 * kk + 8 * hi]);

    f32x4 acc[4] = {};
    float m_run = -INFINITY, l_run = 0.f;

    for (int kv0 = 0; kv0 < SS; kv0 += 64) {
        bf16x8 kr0 = *reinterpret_cast<const bf16x8*>(
            (const char*)&khp[(size_t)(kv0 + srow) * DKK] + gcb);
        bf16x8 kr1 = *reinterpret_cast<const bf16x8*>(
            (const char*)&khp[(size_t)(kv0 + srow + 8) * DKK] + gcb);
        bf16x8 vr0 = *reinterpret_cast<const bf16x8*>(
            (const char*)&vtp[(size_t)srow * SS + kv0] + gcb);
        bf16x8 vr1 = *reinterpret_cast<const bf16x8*>(
            (const char*)&vtp[(size_t)(srow + 8) * SS + kv0] + gcb);

        __syncthreads();
        *reinterpret_cast<bf16x8*>(KsB  + srow * 128 + scb)       = kr0;
        *reinterpret_cast<bf16x8*>(KsB  + (srow + 8) * 128 + scb) = kr1;
        *reinterpret_cast<bf16x8*>(VtsB + srow * 128 + scb)       = vr0;
        *reinterpret_cast<bf16x8*>(VtsB + (srow + 8) * 128 + scb) = vr1;
        __syncthreads();

        // scores: S^T[kv 64][q 16] via mfma(K, Q)
        f32x4 sc[4] = {};
#pragma unroll
        for (int kk = 0; kk < 2; ++kk) {
            bf16x8 kf[4];
#pragma unroll
            for (int f = 0; f < 4; ++f) {
                const int row = 16 * f + lo;
                const int cb  = (64 * kk + 16 * hi) ^ ((row & 7) << 4);
                kf[f] = *reinterpret_cast<const bf16x8*>(KsB + row * 128 + cb);
            }
#pragma unroll
            for (int f = 0; f < 4; ++f)
                sc[f] = MFMA16(kf[f], qf[kk], sc[f]);
        }

        // online softmax (lane owns q = lo)
        {
            float mx = -1e30f;
#pragma unroll
            for (int f = 0; f < 4; ++f)
#pragma unroll
                for (int r = 0; r < 4; ++r)
                    mx = fmaxf(mx, sc[f][r]);
            mx = fmaxf(mx, __shfl_xor(mx, 16));
            mx = fmaxf(mx, __shfl_xor(mx, 32));
            const float mnew = fmaxf(m_run, mx * 0.125f);
            const float scl  = __expf(m_run - mnew);
            float rs = 0.f;
#pragma unroll
            for (int f = 0; f < 4; ++f) {
                bf16x4 pk;
#pragma unroll
                for (int r = 0; r < 4; ++r) {
                    const float e = __expf(fmaf(sc[f][r], 0.125f, -mnew));
                    rs += e;
                    pk[r] = (__bf16)e;
                }
                *reinterpret_cast<bf16x4*>(&Ps[wid][lo][16 * f + 4 * hi]) = pk;
            }
            rs += __shfl_xor(rs, 16);
            rs += __shfl_xor(rs, 32);
            l_run = l_run * scl + rs;
            m_run = mnew;
#pragma unroll
            for (int f = 0; f < 4; ++f)
                acc[f] *= scl;
        }

        // PV: O^T += mfma(V^T, P^T)
#pragma unroll
        for (int kk = 0; kk < 2; ++kk) {
            bf16x8 pb = *reinterpret_cast<const bf16x8*>(&Ps[wid][lo][32 * kk + 8 * hi]);
#pragma unroll
            for (int f = 0; f < 4; ++f) {
                const int row = 16 * f + lo;
                const int cb  = (64 * kk + 16 * hi) ^ ((row & 7) << 4);
                bf16x8 vf = *reinterpret_cast<const bf16x8*>(VtsB + row * 128 + cb);
                acc[f] = MFMA16(vf, pb, acc[f]);
            }
        }
    }

    {
        const float inv = 1.0f / l_run;
        const int qrow = q0 + 16 * wid + lo;
        const size_t ob = ((size_t)b_ * SS + qrow) * HDK + h_ * DKK;
#pragma unroll
        for (int f = 0; f < 4; ++f) {
            bf16x4 o;
#pragma unroll
            for (int r = 0; r < 4; ++r)
                o[r] = (__bf16)(acc[f][r] * inv);
            *reinterpret_cast<bf16x4*>(&concat[ob + 16 * f + 4 * hi]) = o;
        }
    }
}

// ---------------------------------------------------------------------------
// Kernel 3: output projection, 128x128xBK64, gload_lds staging.
// A = concat (bf16, direct), B = Wout (fp32, cvt at fragment read).
// ---------------------------------------------------------------------------
__global__ __launch_bounds__(256) void outproj_kernel(
    const __bf16* __restrict__ concat, const float* __restrict__ Wout,
    const float* __restrict__ bout, float* __restrict__ out)
{
    const int m0 = blockIdx.x * 128;
    const int n0 = blockIdx.y * 128;

    __shared__ __align__(16) __bf16 As[128 * 64];  // 16 KB, chunk-swizzled
    __shared__ __align__(16) float  Bs[128 * 64];  // 32 KB, chunk-swizzled

    const int t    = threadIdx.x;
    const int lane = t & 63, wid = t >> 6;
    const int lo   = lane & 15, hi = lane >> 4;
    const int wm   = wid >> 1, wn = wid & 1;

    f32x4 acc[4][4] = {};

    for (int k0 = 0; k0 < HDK; k0 += 64) {
        __syncthreads();
        // A (bf16): 4 issues/wave, 8 rows x 128 B each
#pragma unroll
        for (int i = 0; i < 4; ++i) {
            const int r0  = 32 * wid + 8 * i;
            const int row = r0 + (lane >> 3);
            const int gco = ((lane & 7) ^ (row & 7)) << 4;
            GLOAD_LDS16((const char*)&concat[(size_t)(m0 + row) * HDK + k0] + gco,
                        (char*)As + r0 * 128);
        }
        // B (fp32): 8 issues/wave, 4 rows x 256 B each
#pragma unroll
        for (int i = 0; i < 8; ++i) {
            const int r0  = 32 * wid + 4 * i;
            const int row = r0 + (lane >> 4);
            const int gco = ((lane & 15) ^ (row & 7)) << 4;
            GLOAD_LDS16((const char*)&Wout[(size_t)(n0 + row) * HDK + k0] + gco,
                        (char*)Bs + r0 * 256);
        }
        __syncthreads();

#pragma unroll
        for (int kk = 0; kk < 2; ++kk) {
            bf16x8 a[4], b[4];
#pragma unroll
            for (int mi = 0; mi < 4; ++mi) {
                const int ar = wm * 64 + mi * 16 + lo;
                const int cb = (kk * 64 + hi * 16) ^ ((ar & 7) << 4);
                a[mi] = *reinterpret_cast<const bf16x8*>((const char*)As + ar * 128 + cb);
            }
#pragma unroll
            for (int ni = 0; ni < 4; ++ni) {
                const int br = wn * 64 + ni * 16 + lo;
                const int rs = (br & 7) << 4;
                const int cb = kk * 128 + hi * 32;
                f32x4 f0 = *reinterpret_cast<const f32x4*>((const char*)Bs + br * 256 + (cb ^ rs));
                f32x4 f1 = *reinterpret_cast<const f32x4*>((const char*)Bs + br * 256 + ((cb + 16) ^ rs));
                b[ni] = cvt48(f0, f1);
            }
#pragma unroll
            for (int mi = 0; mi < 4; ++mi)
#pragma unroll
                for (int ni = 0; ni < 4; ++ni)
                    acc[mi][ni] = MFMA16(a[mi], b[ni], acc[mi][ni]);
        }
    }

#pragma unroll
    for (int mi = 0; mi < 4; ++mi) {
#pragma unroll
        for (int ni = 0; ni < 4; ++ni) {
            const int n = n0 + wn * 64 + ni * 16 + lo;
            const float bias = bout[n];
#pragma unroll
            for (int r = 0; r < 4; ++r) {
                const int m = m0 + wm * 64 + mi * 16 + hi * 4 + r;
                out[(size_t)m * DD + n] = acc[mi][ni][r] + bias;
            }
        }
    }
}

// ---------------------------------------------------------------------------
extern "C" void kernel_launch(void* const* d_in, const int* in_sizes, int n_in,
                              void* d_out, int out_size, void* d_ws, size_t ws_size,
                              hipStream_t stream)
{
    (void)in_sizes; (void)n_in; (void)out_size; (void)ws_size;
    const float* q    = (const float*)d_in[0];
    const float* k    = (const float*)d_in[1];
    const float* v    = (const float*)d_in[2];
    const float* Wq   = (const float*)d_in[3];
    const float* bq   = (const float*)d_in[4];
    const float* Wout = (const float*)d_in[5];
    const float* bout = (const float*)d_in[6];
    float* out = (float*)d_out;

    char* ws = (char*)d_ws;
    __bf16* qh = (__bf16*)(ws);                      // 8 MiB  [B,H,S,DK]
    __bf16* kh = (__bf16*)(ws + (8u << 20));         // 8 MiB  [B,H,S,DK]
    __bf16* vt = (__bf16*)(ws + (16u << 20));        // 8 MiB  [B,H,DK,S]
    __bf16* cc = (__bf16*)(ws + (24u << 20));        // 8 MiB  [B,S,H*DK]

    proj_kernel<<<dim3(BB * SS / 128, HDK / 128, 3), 256, 0, stream>>>(q, k, v, Wq, bq, qh, kh, vt);
    attn_kernel<<<dim3(SS / 64, BB * HH), 256, 0, stream>>>(qh, kh, vt, cc);
    outproj_kernel<<<dim3(BB * SS / 128, DD / 128), 256, 0, stream>>>(cc, Wout, bout, out);
}